// Round 7
// baseline (169.117 us; speedup 1.0000x reference)
//
#include <hip/hip_runtime.h>

#define VOCAB 50257
#define EMBD  300
#define EMBP  320      // EMB padded to multiple of 32 for MFMA K
#define HID   1024
#define B3H   3072
#define BATCH 128
#define WROWS 32       // vocab rows per k3 block
#define NBLK3 1571     // ceil(50257/32)
#define NKT   32       // K tiles of 32 in k3

typedef __attribute__((ext_vector_type(8))) short short8;
typedef __attribute__((ext_vector_type(4))) short short4s;
typedef __attribute__((ext_vector_type(4))) float f32x4;
typedef unsigned short ushort_t;

__device__ __forceinline__ unsigned short f2bf(float f) {
  unsigned int u = __float_as_uint(f);
  u += 0x7fffu + ((u >> 16) & 1u);
  return (unsigned short)(u >> 16);
}

__device__ __forceinline__ void gload16(const void* g, void* l) {
  __builtin_amdgcn_global_load_lds(
      (const __attribute__((address_space(1))) void*)g,
      (__attribute__((address_space(3))) void*)l, 16, 0, 0);
}

#define MEMF() asm volatile("" ::: "memory")

// ---------------- K0: gather + bf16 casts (x, h, w_ih, w_hh) ----------------
__global__ __launch_bounds__(256) void k0_prep(
    const int* __restrict__ ids, const float* __restrict__ emb,
    const float* __restrict__ hprev, const float* __restrict__ wih,
    const float* __restrict__ whh,
    ushort_t* __restrict__ xbf, ushort_t* __restrict__ hbf,
    ushort_t* __restrict__ wihbf, ushort_t* __restrict__ whhbf) {
  const int NX  = BATCH * EMBP;        // 40960
  const int NH  = BATCH * HID;         // 131072
  const int NWI = B3H * EMBP;          // 983040
  int i = blockIdx.x * 256 + threadIdx.x;
  if (i < NX) {
    int b = i / EMBP, k = i - b * EMBP;
    float f = (k < EMBD) ? emb[(size_t)ids[b] * EMBD + k] : 0.f;
    xbf[i] = f2bf(f);
  } else if (i < NX + NH) {
    int j = i - NX;
    hbf[j] = f2bf(hprev[j]);
  } else if (i < NX + NH + NWI) {
    int j = i - NX - NH;
    int n = j / EMBP, k = j - n * EMBP;
    wihbf[j] = f2bf((k < EMBD) ? wih[(size_t)n * EMBP * 0 + (size_t)n * EMBD + k] : 0.f);
  } else {
    int j = (i - NX - NH - NWI) * 8;
    f32x4 a = *(const f32x4*)(whh + j);
    f32x4 b = *(const f32x4*)(whh + j + 4);
    short8 o;
    o[0] = (short)f2bf(a[0]); o[1] = (short)f2bf(a[1]);
    o[2] = (short)f2bf(a[2]); o[3] = (short)f2bf(a[3]);
    o[4] = (short)f2bf(b[0]); o[5] = (short)f2bf(b[1]);
    o[6] = (short)f2bf(b[2]); o[7] = (short)f2bf(b[3]);
    *(short8*)(whhbf + j) = o;
  }
}

// ---------------- K1: gates GEMMs, 1 wave per block, 16 cols, bf16 B ----------------
__global__ __launch_bounds__(64) void k1_gemm_gates(
    const ushort_t* __restrict__ xbf, const ushort_t* __restrict__ hbf,
    const ushort_t* __restrict__ wihbf, const ushort_t* __restrict__ whhbf,
    float* __restrict__ gi, float* __restrict__ gh) {
  const bool is_h = (blockIdx.y == 1);
  const ushort_t* A = is_h ? hbf : xbf;
  const ushort_t* B = is_h ? whhbf : wihbf;
  const int K = is_h ? HID : EMBP;
  const int lane = threadIdx.x;
  const int r = lane & 15, g = lane >> 4;
  const int n = blockIdx.x * 16 + r;
  const ushort_t* brow = B + (size_t)n * K;

  f32x4 acc[8];
#pragma unroll
  for (int i = 0; i < 8; i++) acc[i] = (f32x4){0.f, 0.f, 0.f, 0.f};

#pragma unroll 2
  for (int k0 = 0; k0 < K; k0 += 32) {
    short8 bfr = *(const short8*)(brow + k0 + g * 8);
#pragma unroll
    for (int mi = 0; mi < 8; mi++) {
      short8 afr = *(const short8*)(A + (size_t)(mi * 16 + r) * K + k0 + g * 8);
      acc[mi] = __builtin_amdgcn_mfma_f32_16x16x32_bf16(afr, bfr, acc[mi], 0, 0, 0);
    }
  }
  float* C = is_h ? gh : gi;
#pragma unroll
  for (int mi = 0; mi < 8; mi++)
#pragma unroll
    for (int rr = 0; rr < 4; rr++)
      C[(size_t)(mi * 16 + g * 4 + rr) * B3H + n] = acc[mi][rr];
}

// ---------------- K2: GRU gates -> h_new (f32) + chunk-major bf16 hnbf2 ----------
// hnbf2 layout: ushort idx = kchunk*1024 + row*8 + (k&7), kchunk = k>>3.
// Tile kt (32 k) of all 128 rows = bytes [kt*8192, kt*8192+8192) CONTIGUOUS.
__global__ __launch_bounds__(256) void k2_gates(
    const float* __restrict__ gi, const float* __restrict__ gh,
    const float* __restrict__ bih, const float* __restrict__ bhh,
    const float* __restrict__ hprev,
    float* __restrict__ hnew_out, ushort_t* __restrict__ hnbf2) {
  int t = blockIdx.x * 256 + threadIdx.x;   // 0..16383
  int row = t >> 7, kc = t & 127;
  int k0 = kc * 8;
  size_t gb = (size_t)row * B3H;
  float hv[8];
  short8 o;
#pragma unroll
  for (int e = 0; e < 8; ++e) {
    int j = k0 + e;
    float ir  = gi[gb + j]           + bih[j];
    float iz  = gi[gb + HID + j]     + bih[HID + j];
    float in_ = gi[gb + 2*HID + j]   + bih[2*HID + j];
    float hr  = gh[gb + j]           + bhh[j];
    float hz  = gh[gb + HID + j]     + bhh[HID + j];
    float hn  = gh[gb + 2*HID + j]   + bhh[2*HID + j];
    float rg = 1.f / (1.f + expf(-(ir + hr)));
    float zg = 1.f / (1.f + expf(-(iz + hz)));
    float ng = tanhf(in_ + rg * hn);
    float h  = hprev[row * HID + j];
    hv[e] = (1.f - zg) * ng + zg * h;
    o[e] = (short)f2bf(hv[e]);
  }
  *(f32x4*)(hnew_out + (size_t)row * HID + k0)     = (f32x4){hv[0], hv[1], hv[2], hv[3]};
  *(f32x4*)(hnew_out + (size_t)row * HID + k0 + 4) = (f32x4){hv[4], hv[5], hv[6], hv[7]};
  *(short8*)(hnbf2 + (size_t)kc * 1024 + row * 8) = o;
}

// ---------------- K3: logits GEMM, W LDS-resident, sequential-row streaming ----
// 256 thr (4 waves), 32 vocab rows, full K=1024.
// Phase 1: waves stream 8 W rows each SEQUENTIALLY (1KB coalesced loads),
//          cvt bf16, ds_write into XOR-swizzled Wl (64 KB).
// Phase 2: 32 K-tiles; A tiles (8KB, chunk-major) via gload16 double-buffer;
//          wave = (cw: vocab col group, mh: batch half); disjoint outputs.
__global__ __launch_bounds__(256, 2) void k3_logits(
    const ushort_t* __restrict__ Abf2, const float* __restrict__ Wout,
    const float* __restrict__ bout, float* __restrict__ out,
    float2* __restrict__ part) {
  __shared__ ushort_t Wl[WROWS * 1024];   // 64 KB
  __shared__ ushort_t At2[2 * 4096];      // 16 KB (2 x 8KB tiles)

  const int lane = threadIdx.x & 63;
  const int wid  = threadIdx.x >> 6;   // 0..3
  const int r = lane & 15, g = lane >> 4;
  const int vb = blockIdx.x * WROWS;

  // ---------- phase 1 ----------
#define LOADQ(Q0, Q1, Q2, Q3, LR)                                        \
  { int vr = vb + (LR); if (vr > VOCAB - 1) vr = VOCAB - 1;              \
    const float* rp = Wout + (size_t)vr * HID;                           \
    Q0 = *(const f32x4*)(rp + lane * 4);                                 \
    Q1 = *(const f32x4*)(rp + 256 + lane * 4);                           \
    Q2 = *(const f32x4*)(rp + 512 + lane * 4);                           \
    Q3 = *(const f32x4*)(rp + 768 + lane * 4); }
#define CVT4(D, Q)                                                       \
  { D[0] = (short)f2bf(Q[0]); D[1] = (short)f2bf(Q[1]);                  \
    D[2] = (short)f2bf(Q[2]); D[3] = (short)f2bf(Q[3]); }
#define CVTW(Q0, Q1, Q2, Q3, LR)                                         \
  { short4s d0, d1, d2, d3;                                              \
    CVT4(d0, Q0) CVT4(d1, Q1) CVT4(d2, Q2) CVT4(d3, Q3)                  \
    const int xo = ((LR) & 7) << 4;                                      \
    char* wb = (char*)Wl + (LR) * 2048;                                  \
    *(short4s*)(wb + ((lane * 8)        ^ xo)) = d0;                     \
    *(short4s*)(wb + ((lane * 8 + 512)  ^ xo)) = d1;                     \
    *(short4s*)(wb + ((lane * 8 + 1024) ^ xo)) = d2;                     \
    *(short4s*)(wb + ((lane * 8 + 1536) ^ xo)) = d3; }

  {
    const int rbase = wid * 8;
    f32x4 qa0, qa1, qa2, qa3, qb0, qb1, qb2, qb3;
    LOADQ(qa0, qa1, qa2, qa3, rbase + 0)
    LOADQ(qb0, qb1, qb2, qb3, rbase + 1)
#pragma unroll
    for (int p = 0; p < 4; ++p) {
      CVTW(qa0, qa1, qa2, qa3, rbase + p * 2)
      if (p < 3) LOADQ(qa0, qa1, qa2, qa3, rbase + p * 2 + 2)
      CVTW(qb0, qb1, qb2, qb3, rbase + p * 2 + 1)
      if (p < 3) LOADQ(qb0, qb1, qb2, qb3, rbase + p * 2 + 3)
    }
  }
#undef LOADQ
#undef CVT4
#undef CVTW

  __syncthreads();

  // ---------- phase 2 ----------
  const int cw = wid & 1;        // vocab col group (16 rows)
  const int mh = wid >> 1;       // batch half (rows mh*64 .. +63)
  const int row_l = cw * 16 + r;
  const int xo = (r & 7) << 4;
  const char* wbase = (const char*)Wl + row_l * 2048;
  const char* abase = (const char*)At2 + g * 2048 + (mh * 64 + r) * 16;

  f32x4 acc[4];
#pragma unroll
  for (int i = 0; i < 4; ++i) acc[i] = (f32x4){0.f, 0.f, 0.f, 0.f};

#define AISSUE(KT)                                                        \
  { const char* src = (const char*)Abf2 + (size_t)(KT) * 8192 +           \
                      (wid * 2) * 1024 + lane * 16;                       \
    char* dst = (char*)At2 + ((KT) & 1) * 8192 + (wid * 2) * 1024;        \
    gload16(src, dst);                                                    \
    gload16(src + 1024, dst + 1024); }

  AISSUE(0)
  for (int kt = 0; kt < NKT; ++kt) {
    asm volatile("s_waitcnt vmcnt(0)" ::: "memory");
    __builtin_amdgcn_s_barrier(); MEMF();
    if (kt + 1 < NKT) { AISSUE(kt + 1) MEMF(); }
    short8 bfr = *(const short8*)(wbase + ((kt * 64 + g * 16) ^ xo));
    const char* ab = abase + (kt & 1) * 8192;
#pragma unroll
    for (int mi = 0; mi < 4; ++mi) {
      short8 afr = *(const short8*)(ab + mi * 256);
      acc[mi] = __builtin_amdgcn_mfma_f32_16x16x32_bf16(afr, bfr, acc[mi], 0, 0, 0);
    }
  }
#undef AISSUE

  // ---------- epilogue: bias, store logits, softmax partials ----------
  const int v = vb + cw * 16 + r;
  const bool vok = (v < VOCAB);
  float bias = bout[vok ? v : VOCAB - 1];
#pragma unroll
  for (int mi = 0; mi < 4; ++mi) {
#pragma unroll
    for (int rr = 0; rr < 4; ++rr) {
      float val = acc[mi][rr] + bias;
      int b = mh * 64 + mi * 16 + g * 4 + rr;
      if (vok) out[(size_t)b * VOCAB + v] = val;
      float sv = vok ? val : -INFINITY;
      float m = sv;
      m = fmaxf(m, __shfl_xor(m, 1));
      m = fmaxf(m, __shfl_xor(m, 2));
      m = fmaxf(m, __shfl_xor(m, 4));
      m = fmaxf(m, __shfl_xor(m, 8));
      float ss = vok ? __expf(sv - m) : 0.f;
      ss += __shfl_xor(ss, 1);
      ss += __shfl_xor(ss, 2);
      ss += __shfl_xor(ss, 4);
      ss += __shfl_xor(ss, 8);
      if (r == 0) part[((size_t)blockIdx.x * 2 + cw) * 128 + b] = make_float2(m, ss);
    }
  }
}

// ---------------- K4: combine partials -> stat[b] ----------------
__global__ __launch_bounds__(256) void k4_combine(
    const float2* __restrict__ part, float* __restrict__ stat) {
  const int NP = NBLK3 * 2;   // 3142
  int b = blockIdx.x, t = threadIdx.x;
  float m = -INFINITY;
  for (int i = t; i < NP; i += 256) m = fmaxf(m, part[(size_t)i * 128 + b].x);
  __shared__ float red[256];
  red[t] = m; __syncthreads();
  for (int s = 128; s > 0; s >>= 1) {
    if (t < s) red[t] = fmaxf(red[t], red[t + s]);
    __syncthreads();
  }
  float M = red[0]; __syncthreads();
  float ssum = 0.f;
  for (int i = t; i < NP; i += 256) {
    float2 p = part[(size_t)i * 128 + b];
    ssum += p.y * __expf(p.x - M);
  }
  red[t] = ssum; __syncthreads();
  for (int s = 128; s > 0; s >>= 1) {
    if (t < s) red[t] += red[t + s];
    __syncthreads();
  }
  if (t == 0) stat[b] = M + logf(red[0]);
}

// ---------------- K5: out = logit - stat[b], float4 ----------------
__global__ __launch_bounds__(256) void k5_final(
    float* __restrict__ out, const float* __restrict__ stat) {
  const int total = BATCH * VOCAB;        // 6432896, divisible by 4
  int i4 = blockIdx.x * 256 + threadIdx.x;
  int base = i4 * 4;
  if (base >= total) return;
  float4 v = *(float4*)(out + base);
  int b0 = base / VOCAB, b3 = (base + 3) / VOCAB;
  if (b0 == b3) {
    float s = stat[b0];
    v.x -= s; v.y -= s; v.z -= s; v.w -= s;
  } else {
    v.x -= stat[base / VOCAB];
    v.y -= stat[(base + 1) / VOCAB];
    v.z -= stat[(base + 2) / VOCAB];
    v.w -= stat[(base + 3) / VOCAB];
  }
  *(float4*)(out + base) = v;
}

extern "C" void kernel_launch(void* const* d_in, const int* in_sizes, int n_in,
                              void* d_out, int out_size, void* d_ws, size_t ws_size,
                              hipStream_t stream) {
  const int*   ids   = (const int*)  d_in[0];
  const float* hprev = (const float*)d_in[1];
  // d_in[2] = encoder_output, unused by the reference
  const float* emb   = (const float*)d_in[3];
  const float* wih   = (const float*)d_in[4];
  const float* whh   = (const float*)d_in[5];
  const float* bih   = (const float*)d_in[6];
  const float* bhh   = (const float*)d_in[7];
  const float* Wout  = (const float*)d_in[8];
  const float* bout  = (const float*)d_in[9];
  float* out = (float*)d_out;
  char* ws = (char*)d_ws;

  // ws layout (bytes); max offset used = 12009472 (same as R3-R6).
  // hnbf2 aliases dead wihbf region; part/stat alias dead whhbf region.
  ushort_t* xbf   = (ushort_t*)(ws + 0);         // 128x320 bf16
  ushort_t* hbf   = (ushort_t*)(ws + 81920);     // 128x1024 bf16
  ushort_t* wihbf = (ushort_t*)(ws + 344064);    // 3072x320 bf16 (dead after k1)
  ushort_t* whhbf = (ushort_t*)(ws + 2310144);   // 3072x1024 bf16 (dead after k1)
  float*    gi    = (float*)(ws + 8601600);      // 128x3072 f32
  float*    gh    = (float*)(ws + 10174464);     // 128x3072 f32
  ushort_t* hnbf2 = (ushort_t*)(ws + 344064);    // 128x1024 bf16 chunk-major (aliases wihbf)
  float2*   part  = (float2*)(ws + 2310144);     // 3142x128 float2 (aliases whhbf)
  float*    stat  = (float*)(ws + 5529600);      // 128 f32

  float* hnew_out = out + (size_t)BATCH * VOCAB;

  hipLaunchKernelGGL(k0_prep, dim3(6048), dim3(256), 0, stream,
                     ids, emb, hprev, wih, whh, xbf, hbf, wihbf, whhbf);
  hipLaunchKernelGGL(k1_gemm_gates, dim3(192, 2), dim3(64), 0, stream,
                     xbf, hbf, wihbf, whhbf, gi, gh);
  hipLaunchKernelGGL(k2_gates, dim3(64), dim3(256), 0, stream,
                     gi, gh, bih, bhh, hprev, hnew_out, hnbf2);
  hipLaunchKernelGGL(k3_logits, dim3(NBLK3), dim3(256), 0, stream,
                     hnbf2, Wout, bout, out, part);
  hipLaunchKernelGGL(k4_combine, dim3(128), dim3(256), 0, stream, part, stat);
  hipLaunchKernelGGL(k5_final, dim3((BATCH * VOCAB / 4 + 255) / 256), dim3(256), 0, stream,
                     out, stat);
}

// Round 8
// 167.237 us; speedup vs baseline: 1.0112x; 1.0112x over previous
//
#include <hip/hip_runtime.h>

#define VOCAB 50257
#define EMBD  300
#define EMBP  320      // EMB padded to multiple of 32 for MFMA K
#define HID   1024
#define B3H   3072
#define BATCH 128
#define NBK3  3142     // ceil(50257/16) : k3 grid, 16 vocab rows/block
#define NKT   32       // K tiles of 32

typedef __attribute__((ext_vector_type(8))) short short8;
typedef __attribute__((ext_vector_type(4))) float f32x4;
typedef unsigned short ushort_t;

__device__ __forceinline__ unsigned short f2bf(float f) {
  unsigned int u = __float_as_uint(f);
  u += 0x7fffu + ((u >> 16) & 1u);
  return (unsigned short)(u >> 16);
}

__device__ __forceinline__ void gload16(const void* g, void* l) {
  __builtin_amdgcn_global_load_lds(
      (const __attribute__((address_space(1))) void*)g,
      (__attribute__((address_space(3))) void*)l, 16, 0, 0);
}

#define MEMF() asm volatile("" ::: "memory")

// ---------------- K0: gather + bf16 casts (x, h, w_ih, w_hh) ----------------
__global__ __launch_bounds__(256) void k0_prep(
    const int* __restrict__ ids, const float* __restrict__ emb,
    const float* __restrict__ hprev, const float* __restrict__ wih,
    const float* __restrict__ whh,
    ushort_t* __restrict__ xbf, ushort_t* __restrict__ hbf,
    ushort_t* __restrict__ wihbf, ushort_t* __restrict__ whhbf) {
  const int NX  = BATCH * EMBP;        // 40960
  const int NH  = BATCH * HID;         // 131072
  const int NWI = B3H * EMBP;          // 983040
  int i = blockIdx.x * 256 + threadIdx.x;
  if (i < NX) {
    int b = i / EMBP, k = i - b * EMBP;
    float f = (k < EMBD) ? emb[(size_t)ids[b] * EMBD + k] : 0.f;
    xbf[i] = f2bf(f);
  } else if (i < NX + NH) {
    int j = i - NX;
    hbf[j] = f2bf(hprev[j]);
  } else if (i < NX + NH + NWI) {
    int j = i - NX - NH;
    int n = j / EMBP, k = j - n * EMBP;
    wihbf[j] = f2bf((k < EMBD) ? wih[(size_t)n * EMBD + k] : 0.f);
  } else {
    int j = (i - NX - NH - NWI) * 8;
    f32x4 a = *(const f32x4*)(whh + j);
    f32x4 b = *(const f32x4*)(whh + j + 4);
    short8 o;
    o[0] = (short)f2bf(a[0]); o[1] = (short)f2bf(a[1]);
    o[2] = (short)f2bf(a[2]); o[3] = (short)f2bf(a[3]);
    o[4] = (short)f2bf(b[0]); o[5] = (short)f2bf(b[1]);
    o[6] = (short)f2bf(b[2]); o[7] = (short)f2bf(b[3]);
    *(short8*)(whhbf + j) = o;
  }
}

// ---------------- K1: gates GEMMs, 1 wave per block, 16 cols, bf16 B ----------------
__global__ __launch_bounds__(64) void k1_gemm_gates(
    const ushort_t* __restrict__ xbf, const ushort_t* __restrict__ hbf,
    const ushort_t* __restrict__ wihbf, const ushort_t* __restrict__ whhbf,
    float* __restrict__ gi, float* __restrict__ gh) {
  const bool is_h = (blockIdx.y == 1);
  const ushort_t* A = is_h ? hbf : xbf;
  const ushort_t* B = is_h ? whhbf : wihbf;
  const int K = is_h ? HID : EMBP;
  const int lane = threadIdx.x;
  const int r = lane & 15, g = lane >> 4;
  const int n = blockIdx.x * 16 + r;
  const ushort_t* brow = B + (size_t)n * K;

  f32x4 acc[8];
#pragma unroll
  for (int i = 0; i < 8; i++) acc[i] = (f32x4){0.f, 0.f, 0.f, 0.f};

#pragma unroll 2
  for (int k0 = 0; k0 < K; k0 += 32) {
    short8 bfr = *(const short8*)(brow + k0 + g * 8);
#pragma unroll
    for (int mi = 0; mi < 8; mi++) {
      short8 afr = *(const short8*)(A + (size_t)(mi * 16 + r) * K + k0 + g * 8);
      acc[mi] = __builtin_amdgcn_mfma_f32_16x16x32_bf16(afr, bfr, acc[mi], 0, 0, 0);
    }
  }
  float* C = is_h ? gh : gi;
#pragma unroll
  for (int mi = 0; mi < 8; mi++)
#pragma unroll
    for (int rr = 0; rr < 4; rr++)
      C[(size_t)(mi * 16 + g * 4 + rr) * B3H + n] = acc[mi][rr];
}

// ---------------- K2: GRU gates -> h_new (f32) + chunk-major bf16 hnbf2 ----------
// hnbf2 layout: ushort idx = kchunk*1024 + row*8 + (k&7), kchunk = k>>3.
// K-tile kt (32 k) of all 128 rows = bytes [kt*8192, kt*8192+8192) CONTIGUOUS.
__global__ __launch_bounds__(256) void k2_gates(
    const float* __restrict__ gi, const float* __restrict__ gh,
    const float* __restrict__ bih, const float* __restrict__ bhh,
    const float* __restrict__ hprev,
    float* __restrict__ hnew_out, ushort_t* __restrict__ hnbf2) {
  int t = blockIdx.x * 256 + threadIdx.x;   // 0..16383
  int row = t >> 7, kc = t & 127;
  int k0 = kc * 8;
  size_t gb = (size_t)row * B3H;
  float hv[8];
  short8 o;
#pragma unroll
  for (int e = 0; e < 8; ++e) {
    int j = k0 + e;
    float ir  = gi[gb + j]           + bih[j];
    float iz  = gi[gb + HID + j]     + bih[HID + j];
    float in_ = gi[gb + 2*HID + j]   + bih[2*HID + j];
    float hr  = gh[gb + j]           + bhh[j];
    float hz  = gh[gb + HID + j]     + bhh[HID + j];
    float hn  = gh[gb + 2*HID + j]   + bhh[2*HID + j];
    float rg = 1.f / (1.f + expf(-(ir + hr)));
    float zg = 1.f / (1.f + expf(-(iz + hz)));
    float ng = tanhf(in_ + rg * hn);
    float h  = hprev[row * HID + j];
    hv[e] = (1.f - zg) * ng + zg * h;
    o[e] = (short)f2bf(hv[e]);
  }
  *(f32x4*)(hnew_out + (size_t)row * HID + k0)     = (f32x4){hv[0], hv[1], hv[2], hv[3]};
  *(f32x4*)(hnew_out + (size_t)row * HID + k0 + 4) = (f32x4){hv[4], hv[5], hv[6], hv[7]};
  *(short8*)(hnbf2 + (size_t)kc * 1024 + row * 8) = o;
}

// ---------------- K3: logits GEMM — 1-wave blocks, deep gload16 ring ----------------
// Block = 1 wave, 16 vocab rows, all 128 batch, K=1024 in 32 tiles.
// Slot (10 KB LDS) = W-tile (16x32 f32, 2KB, source-chunk XOR-swizzled)
//                  + A-tile (8KB contiguous chunk-major hnbf2).
// Ring of 4 slots (40KB LDS). 10 gload16/slot. NO barriers; counted vmcnt only:
// 3 slots (30 loads, 30KB) in flight at all times -> ~120KB/CU issued.
__global__ __launch_bounds__(64) void k3_logits(
    const ushort_t* __restrict__ Abf2, const float* __restrict__ Wout,
    const float* __restrict__ bout, float* __restrict__ out,
    float2* __restrict__ part) {
  __shared__ ushort_t At[4 * 5120];   // 40 KB

  const int l = threadIdx.x;          // 0..63
  const int r = l & 15, g = l >> 4;
  const int vb = blockIdx.x * 16;

  const int srow = l >> 3;            // staging: W row within 8-row group
  const int swz  = (l & 7) ^ srow;    // staging: W source 16B chunk (XOR swizzle)

  f32x4 acc[8];
#pragma unroll
  for (int i = 0; i < 8; ++i) acc[i] = (f32x4){0.f, 0.f, 0.f, 0.f};

  // stage slot for K-tile T: 2 W gloads + 8 A gloads (all dst wave-uniform, linear)
#define STAGE(T)                                                             \
  {                                                                          \
    char* sb = (char*)At + (size_t)((T) & 3) * 10240;                        \
    _Pragma("unroll")                                                        \
    for (int i = 0; i < 2; ++i) {                                            \
      int rw = vb + i * 8 + srow; if (rw > VOCAB - 1) rw = VOCAB - 1;        \
      gload16((const char*)Wout + (size_t)rw * 4096 + (size_t)(T) * 128 + swz * 16, \
              sb + i * 1024);                                                \
    }                                                                        \
    _Pragma("unroll")                                                        \
    for (int i = 0; i < 8; ++i) {                                            \
      gload16((const char*)Abf2 + (size_t)(T) * 8192 + i * 1024 + l * 16,    \
              sb + 2048 + i * 1024);                                         \
    }                                                                        \
  }

  STAGE(0) MEMF();
  STAGE(1) MEMF();
  STAGE(2) MEMF();

  for (int t = 0; t < NKT; ++t) {
    // retire slot t's 10 loads; keep later slots in flight (never drain mid-loop)
    if (t < NKT - 2)       { asm volatile("s_waitcnt vmcnt(20)" ::: "memory"); }
    else if (t == NKT - 2) { asm volatile("s_waitcnt vmcnt(10)" ::: "memory"); }
    else                   { asm volatile("s_waitcnt vmcnt(0)"  ::: "memory"); }
    if (t + 3 < NKT) { STAGE(t + 3) MEMF(); }

    const char* slot = (const char*)At + (size_t)(t & 3) * 10240;
    // W fragment: row r, logical chunks 2g, 2g+1 live at (chunk ^ (r&7))
    f32x4 w0 = *(const f32x4*)(slot + r * 128 + (((2 * g)    ^ (r & 7)) * 16));
    f32x4 w1 = *(const f32x4*)(slot + r * 128 + (((2 * g + 1) ^ (r & 7)) * 16));
    short8 bfr;
    bfr[0] = (short)f2bf(w0[0]); bfr[1] = (short)f2bf(w0[1]);
    bfr[2] = (short)f2bf(w0[2]); bfr[3] = (short)f2bf(w0[3]);
    bfr[4] = (short)f2bf(w1[0]); bfr[5] = (short)f2bf(w1[1]);
    bfr[6] = (short)f2bf(w1[2]); bfr[7] = (short)f2bf(w1[3]);
    // A fragments: kc_local = g, row = mi*16 + r -> offset 2048 + g*2048 + row*16
    const char* ar = slot + 2048 + g * 2048 + r * 16;
#pragma unroll
    for (int mi = 0; mi < 8; ++mi) {
      short8 afr = *(const short8*)(ar + mi * 256);
      acc[mi] = __builtin_amdgcn_mfma_f32_16x16x32_bf16(afr, bfr, acc[mi], 0, 0, 0);
    }
  }
#undef STAGE

  // ---- epilogue: bias, store logits, per-block softmax partials ----
  const int v = vb + r;
  const bool vok = (v < VOCAB);
  float bias = bout[vok ? v : VOCAB - 1];
#pragma unroll
  for (int mi = 0; mi < 8; ++mi) {
#pragma unroll
    for (int rr = 0; rr < 4; ++rr) {
      float val = acc[mi][rr] + bias;
      int b = mi * 16 + g * 4 + rr;          // batch row
      if (vok) out[(size_t)b * VOCAB + v] = val;
      float sv = vok ? val : -INFINITY;
      float m = sv;
      m = fmaxf(m, __shfl_xor(m, 1));
      m = fmaxf(m, __shfl_xor(m, 2));
      m = fmaxf(m, __shfl_xor(m, 4));
      m = fmaxf(m, __shfl_xor(m, 8));
      float ss = vok ? __expf(sv - m) : 0.f;
      ss += __shfl_xor(ss, 1);
      ss += __shfl_xor(ss, 2);
      ss += __shfl_xor(ss, 4);
      ss += __shfl_xor(ss, 8);
      if (r == 0) part[(size_t)blockIdx.x * 128 + b] = make_float2(m, ss);
    }
  }
}

// ---------------- K4: combine partials -> stat[b] ----------------
__global__ __launch_bounds__(256) void k4_combine(
    const float2* __restrict__ part, float* __restrict__ stat) {
  const int NP = NBK3;   // 3142 partials per batch row
  int b = blockIdx.x, t = threadIdx.x;
  float m = -INFINITY;
  for (int i = t; i < NP; i += 256) m = fmaxf(m, part[(size_t)i * 128 + b].x);
  __shared__ float red[256];
  red[t] = m; __syncthreads();
  for (int s = 128; s > 0; s >>= 1) {
    if (t < s) red[t] = fmaxf(red[t], red[t + s]);
    __syncthreads();
  }
  float M = red[0]; __syncthreads();
  float ssum = 0.f;
  for (int i = t; i < NP; i += 256) {
    float2 p = part[(size_t)i * 128 + b];
    ssum += p.y * __expf(p.x - M);
  }
  red[t] = ssum; __syncthreads();
  for (int s = 128; s > 0; s >>= 1) {
    if (t < s) red[t] += red[t + s];
    __syncthreads();
  }
  if (t == 0) stat[b] = M + logf(red[0]);
}

// ---------------- K5: out = logit - stat[b], float4 ----------------
__global__ __launch_bounds__(256) void k5_final(
    float* __restrict__ out, const float* __restrict__ stat) {
  const int total = BATCH * VOCAB;        // 6432896, divisible by 4
  int i4 = blockIdx.x * 256 + threadIdx.x;
  int base = i4 * 4;
  if (base >= total) return;
  float4 v = *(float4*)(out + base);
  int b0 = base / VOCAB, b3 = (base + 3) / VOCAB;
  if (b0 == b3) {
    float s = stat[b0];
    v.x -= s; v.y -= s; v.z -= s; v.w -= s;
  } else {
    v.x -= stat[base / VOCAB];
    v.y -= stat[(base + 1) / VOCAB];
    v.z -= stat[(base + 2) / VOCAB];
    v.w -= stat[(base + 3) / VOCAB];
  }
  *(float4*)(out + base) = v;
}

extern "C" void kernel_launch(void* const* d_in, const int* in_sizes, int n_in,
                              void* d_out, int out_size, void* d_ws, size_t ws_size,
                              hipStream_t stream) {
  const int*   ids   = (const int*)  d_in[0];
  const float* hprev = (const float*)d_in[1];
  // d_in[2] = encoder_output, unused by the reference
  const float* emb   = (const float*)d_in[3];
  const float* wih   = (const float*)d_in[4];
  const float* whh   = (const float*)d_in[5];
  const float* bih   = (const float*)d_in[6];
  const float* bhh   = (const float*)d_in[7];
  const float* Wout  = (const float*)d_in[8];
  const float* bout  = (const float*)d_in[9];
  float* out = (float*)d_out;
  char* ws = (char*)d_ws;

  // ws layout (bytes); max offset used = 12009472 (same as R3-R7).
  // hnbf2 aliases dead wihbf region; part/stat alias dead whhbf region.
  ushort_t* xbf   = (ushort_t*)(ws + 0);         // 128x320 bf16
  ushort_t* hbf   = (ushort_t*)(ws + 81920);     // 128x1024 bf16
  ushort_t* wihbf = (ushort_t*)(ws + 344064);    // 3072x320 bf16 (dead after k1)
  ushort_t* whhbf = (ushort_t*)(ws + 2310144);   // 3072x1024 bf16 (dead after k1)
  float*    gi    = (float*)(ws + 8601600);      // 128x3072 f32
  float*    gh    = (float*)(ws + 10174464);     // 128x3072 f32
  ushort_t* hnbf2 = (ushort_t*)(ws + 344064);    // 128x1024 bf16 chunk-major (aliases wihbf)
  float2*   part  = (float2*)(ws + 2310144);     // 3142x128 float2 (aliases whhbf)
  float*    stat  = (float*)(ws + 5529600);      // 128 f32

  float* hnew_out = out + (size_t)BATCH * VOCAB;

  hipLaunchKernelGGL(k0_prep, dim3(6048), dim3(256), 0, stream,
                     ids, emb, hprev, wih, whh, xbf, hbf, wihbf, whhbf);
  hipLaunchKernelGGL(k1_gemm_gates, dim3(192, 2), dim3(64), 0, stream,
                     xbf, hbf, wihbf, whhbf, gi, gh);
  hipLaunchKernelGGL(k2_gates, dim3(64), dim3(256), 0, stream,
                     gi, gh, bih, bhh, hprev, hnew_out, hnbf2);
  hipLaunchKernelGGL(k3_logits, dim3(NBK3), dim3(64), 0, stream,
                     hnbf2, Wout, bout, out, part);
  hipLaunchKernelGGL(k4_combine, dim3(128), dim3(256), 0, stream, part, stat);
  hipLaunchKernelGGL(k5_final, dim3((BATCH * VOCAB / 4 + 255) / 256), dim3(256), 0, stream,
                     out, stat);
}

// Round 10
// 163.982 us; speedup vs baseline: 1.0313x; 1.0198x over previous
//
#include <hip/hip_runtime.h>

#define VOCAB 50257
#define EMBD  300
#define EMBP  320      // EMB padded to multiple of 32 for MFMA K
#define HID   1024
#define B3H   3072
#define BATCH 128
#define NBK3  786      // ceil(50257/64) : k3 grid, 64 vocab rows/block
#define NKT   32       // K tiles of 32
#define SLOTB 16384    // bytes per ring slot: W 8KB + A 8KB

typedef __attribute__((ext_vector_type(8))) short short8;
typedef __attribute__((ext_vector_type(4))) float f32x4;
typedef unsigned short ushort_t;

__device__ __forceinline__ unsigned short f2bf(float f) {
  unsigned int u = __float_as_uint(f);
  u += 0x7fffu + ((u >> 16) & 1u);
  return (unsigned short)(u >> 16);
}

__device__ __forceinline__ void gload16(const void* g, void* l) {
  __builtin_amdgcn_global_load_lds(
      (const __attribute__((address_space(1))) void*)g,
      (__attribute__((address_space(3))) void*)l, 16, 0, 0);
}

#define MEMF() asm volatile("" ::: "memory")

// ---------------- K0: gather + bf16 casts (x, h, w_ih, w_hh) ----------------
__global__ __launch_bounds__(256) void k0_prep(
    const int* __restrict__ ids, const float* __restrict__ emb,
    const float* __restrict__ hprev, const float* __restrict__ wih,
    const float* __restrict__ whh,
    ushort_t* __restrict__ xbf, ushort_t* __restrict__ hbf,
    ushort_t* __restrict__ wihbf, ushort_t* __restrict__ whhbf) {
  const int NX  = BATCH * EMBP;        // 40960
  const int NH  = BATCH * HID;         // 131072
  const int NWI = B3H * EMBP;          // 983040
  int i = blockIdx.x * 256 + threadIdx.x;
  if (i < NX) {
    int b = i / EMBP, k = i - b * EMBP;
    float f = (k < EMBD) ? emb[(size_t)ids[b] * EMBD + k] : 0.f;
    xbf[i] = f2bf(f);
  } else if (i < NX + NH) {
    int j = i - NX;
    hbf[j] = f2bf(hprev[j]);
  } else if (i < NX + NH + NWI) {
    int j = i - NX - NH;
    int n = j / EMBP, k = j - n * EMBP;
    wihbf[j] = f2bf((k < EMBD) ? wih[(size_t)n * EMBD + k] : 0.f);
  } else {
    int j = (i - NX - NH - NWI) * 8;
    f32x4 a = *(const f32x4*)(whh + j);
    f32x4 b = *(const f32x4*)(whh + j + 4);
    short8 o;
    o[0] = (short)f2bf(a[0]); o[1] = (short)f2bf(a[1]);
    o[2] = (short)f2bf(a[2]); o[3] = (short)f2bf(a[3]);
    o[4] = (short)f2bf(b[0]); o[5] = (short)f2bf(b[1]);
    o[6] = (short)f2bf(b[2]); o[7] = (short)f2bf(b[3]);
    *(short8*)(whhbf + j) = o;
  }
}

// ---------------- K1: gates GEMMs, 1 wave per block, 16 cols, bf16 B ----------------
__global__ __launch_bounds__(64) void k1_gemm_gates(
    const ushort_t* __restrict__ xbf, const ushort_t* __restrict__ hbf,
    const ushort_t* __restrict__ wihbf, const ushort_t* __restrict__ whhbf,
    float* __restrict__ gi, float* __restrict__ gh) {
  const bool is_h = (blockIdx.y == 1);
  const ushort_t* A = is_h ? hbf : xbf;
  const ushort_t* B = is_h ? whhbf : wihbf;
  const int K = is_h ? HID : EMBP;
  const int lane = threadIdx.x;
  const int r = lane & 15, g = lane >> 4;
  const int n = blockIdx.x * 16 + r;
  const ushort_t* brow = B + (size_t)n * K;

  f32x4 acc[8];
#pragma unroll
  for (int i = 0; i < 8; i++) acc[i] = (f32x4){0.f, 0.f, 0.f, 0.f};

#pragma unroll 2
  for (int k0 = 0; k0 < K; k0 += 32) {
    short8 bfr = *(const short8*)(brow + k0 + g * 8);
#pragma unroll
    for (int mi = 0; mi < 8; mi++) {
      short8 afr = *(const short8*)(A + (size_t)(mi * 16 + r) * K + k0 + g * 8);
      acc[mi] = __builtin_amdgcn_mfma_f32_16x16x32_bf16(afr, bfr, acc[mi], 0, 0, 0);
    }
  }
  float* C = is_h ? gh : gi;
#pragma unroll
  for (int mi = 0; mi < 8; mi++)
#pragma unroll
    for (int rr = 0; rr < 4; rr++)
      C[(size_t)(mi * 16 + g * 4 + rr) * B3H + n] = acc[mi][rr];
}

// ---------------- K2: GRU gates -> h_new (f32) + chunk-major bf16 hnbf2 ----------
// hnbf2 layout: ushort idx = kchunk*1024 + row*8 + (k&7), kchunk = k>>3.
// K-tile kt (32 k) of all 128 rows = bytes [kt*8192, kt*8192+8192) CONTIGUOUS.
__global__ __launch_bounds__(256) void k2_gates(
    const float* __restrict__ gi, const float* __restrict__ gh,
    const float* __restrict__ bih, const float* __restrict__ bhh,
    const float* __restrict__ hprev,
    float* __restrict__ hnew_out, ushort_t* __restrict__ hnbf2) {
  int t = blockIdx.x * 256 + threadIdx.x;   // 0..16383
  int row = t >> 7, kc = t & 127;
  int k0 = kc * 8;
  size_t gb = (size_t)row * B3H;
  float hv[8];
  short8 o;
#pragma unroll
  for (int e = 0; e < 8; ++e) {
    int j = k0 + e;
    float ir  = gi[gb + j]           + bih[j];
    float iz  = gi[gb + HID + j]     + bih[HID + j];
    float in_ = gi[gb + 2*HID + j]   + bih[2*HID + j];
    float hr  = gh[gb + j]           + bhh[j];
    float hz  = gh[gb + HID + j]     + bhh[HID + j];
    float hn  = gh[gb + 2*HID + j]   + bhh[2*HID + j];
    float rg = 1.f / (1.f + expf(-(ir + hr)));
    float zg = 1.f / (1.f + expf(-(iz + hz)));
    float ng = tanhf(in_ + rg * hn);
    float h  = hprev[row * HID + j];
    hv[e] = (1.f - zg) * ng + zg * h;
    o[e] = (short)f2bf(hv[e]);
  }
  *(f32x4*)(hnew_out + (size_t)row * HID + k0)     = (f32x4){hv[0], hv[1], hv[2], hv[3]};
  *(f32x4*)(hnew_out + (size_t)row * HID + k0 + 4) = (f32x4){hv[4], hv[5], hv[6], hv[7]};
  *(short8*)(hnbf2 + (size_t)kc * 1024 + row * 8) = o;
}

// ---------------- K3: logits GEMM — 1-wave blocks, deep ring, 64 vocab rows ----
// Block = 1 wave, 64 vocab rows x 128 batch, K=1024 in 32 tiles.
// Slot (16 KB) = W-tile (64x32 f32, 8KB, source-chunk XOR-swizzled)
//              + A-tile (8KB contiguous chunk-major hnbf2).
// Ring of 3 slots (48KB -> 3 blocks/CU). 16 gload16/slot. NO barriers;
// counted vmcnt(16): 2 slots (32KB/wave, 96KB/CU) in flight at all times.
// FIX vs R9: slot index computed directly as t%3 / (t+2)%3 (R9's incremental
// rotation was self-cancelling: s never advanced -> stale tiles).
__global__ __launch_bounds__(64) void k3_logits(
    const ushort_t* __restrict__ Abf2, const float* __restrict__ Wout,
    const float* __restrict__ bout, float* __restrict__ out,
    float2* __restrict__ part) {
  __shared__ ushort_t At[3 * SLOTB / 2];   // 48 KB

  const int l = threadIdx.x;          // 0..63
  const int r = l & 15, g = l >> 4;
  const int vb = blockIdx.x * 64;

  const int srow = l >> 3;            // staging: W row within 8-row group
  const int swz  = (l & 7) ^ srow;    // staging: W source 16B chunk (XOR swizzle)

  f32x4 acc[4][8];
#pragma unroll
  for (int c = 0; c < 4; ++c)
#pragma unroll
    for (int m = 0; m < 8; ++m) acc[c][m] = (f32x4){0.f, 0.f, 0.f, 0.f};

  // stage slot for K-tile T into ring slot S: 8 W gloads + 8 A gloads
#define STAGE(T, S)                                                          \
  {                                                                          \
    char* sb = (char*)At + (size_t)(S) * SLOTB;                              \
    _Pragma("unroll")                                                        \
    for (int i = 0; i < 8; ++i) {                                            \
      int rw = vb + i * 8 + srow; if (rw > VOCAB - 1) rw = VOCAB - 1;        \
      gload16((const char*)Wout + (size_t)rw * 4096 + (size_t)(T) * 128 + swz * 16, \
              sb + i * 1024);                                                \
    }                                                                        \
    _Pragma("unroll")                                                        \
    for (int i = 0; i < 8; ++i) {                                            \
      gload16((const char*)Abf2 + (size_t)(T) * 8192 + i * 1024 + l * 16,    \
              sb + 8192 + i * 1024);                                         \
    }                                                                        \
  }

  STAGE(0, 0) MEMF();
  STAGE(1, 1) MEMF();

  for (int t = 0; t < NKT; ++t) {
    // retire slot t's 16 loads; keep slot t+1's 16 in flight (never drain mid-loop)
    if (t < NKT - 1) { asm volatile("s_waitcnt vmcnt(16)" ::: "memory"); }
    else             { asm volatile("s_waitcnt vmcnt(0)"  ::: "memory"); }
    if (t + 2 < NKT) { STAGE(t + 2, ((t + 2) % 3)) MEMF(); }

    const char* slot = (const char*)At + (size_t)(t % 3) * SLOTB;
    // A fragments (shared across all 4 col-groups): kc_local = g, row = m*16+r
    short8 afr[8];
    const char* ar = slot + 8192 + g * 2048 + r * 16;
#pragma unroll
    for (int m = 0; m < 8; ++m) afr[m] = *(const short8*)(ar + m * 256);
    // per col-group c: W row c*16+r, logical chunks 2g,2g+1 at (chunk ^ (r&7))
#pragma unroll
    for (int c = 0; c < 4; ++c) {
      const char* wr = slot + (c * 16 + r) * 128;
      f32x4 w0 = *(const f32x4*)(wr + (((2 * g)     ^ (r & 7)) * 16));
      f32x4 w1 = *(const f32x4*)(wr + (((2 * g + 1) ^ (r & 7)) * 16));
      short8 bfr;
      bfr[0] = (short)f2bf(w0[0]); bfr[1] = (short)f2bf(w0[1]);
      bfr[2] = (short)f2bf(w0[2]); bfr[3] = (short)f2bf(w0[3]);
      bfr[4] = (short)f2bf(w1[0]); bfr[5] = (short)f2bf(w1[1]);
      bfr[6] = (short)f2bf(w1[2]); bfr[7] = (short)f2bf(w1[3]);
#pragma unroll
      for (int m = 0; m < 8; ++m)
        acc[c][m] = __builtin_amdgcn_mfma_f32_16x16x32_bf16(afr[m], bfr, acc[c][m], 0, 0, 0);
    }
  }
#undef STAGE

  // ---- epilogue: bias, store logits, per-block softmax partials ----
#pragma unroll
  for (int m = 0; m < 8; ++m) {
#pragma unroll
    for (int rr = 0; rr < 4; ++rr) {
      int b = m * 16 + g * 4 + rr;          // batch row
      float lm = -INFINITY;
      float vals[4];
#pragma unroll
      for (int c = 0; c < 4; ++c) {
        int v = vb + c * 16 + r;
        bool vok = (v < VOCAB);
        float val = acc[c][m][rr] + bout[vok ? v : VOCAB - 1];
        if (vok) out[(size_t)b * VOCAB + v] = val;
        vals[c] = vok ? val : -INFINITY;
        lm = fmaxf(lm, vals[c]);
      }
      float mx = lm;
      mx = fmaxf(mx, __shfl_xor(mx, 1));
      mx = fmaxf(mx, __shfl_xor(mx, 2));
      mx = fmaxf(mx, __shfl_xor(mx, 4));
      mx = fmaxf(mx, __shfl_xor(mx, 8));
      float ss = 0.f;
#pragma unroll
      for (int c = 0; c < 4; ++c)
        if (vals[c] > -INFINITY) ss += __expf(vals[c] - mx);
      ss += __shfl_xor(ss, 1);
      ss += __shfl_xor(ss, 2);
      ss += __shfl_xor(ss, 4);
      ss += __shfl_xor(ss, 8);
      if (r == 0) part[(size_t)blockIdx.x * 128 + b] = make_float2(mx, ss);
    }
  }
}

// ---------------- K4: combine partials -> stat[b] ----------------
__global__ __launch_bounds__(256) void k4_combine(
    const float2* __restrict__ part, float* __restrict__ stat) {
  const int NP = NBK3;   // 786 partials per batch row
  int b = blockIdx.x, t = threadIdx.x;
  float m = -INFINITY;
  for (int i = t; i < NP; i += 256) m = fmaxf(m, part[(size_t)i * 128 + b].x);
  __shared__ float red[256];
  red[t] = m; __syncthreads();
  for (int st = 128; st > 0; st >>= 1) {
    if (t < st) red[t] = fmaxf(red[t], red[t + st]);
    __syncthreads();
  }
  float M = red[0]; __syncthreads();
  float ssum = 0.f;
  for (int i = t; i < NP; i += 256) {
    float2 p = part[(size_t)i * 128 + b];
    ssum += p.y * __expf(p.x - M);
  }
  red[t] = ssum; __syncthreads();
  for (int st = 128; st > 0; st >>= 1) {
    if (t < st) red[t] += red[t + st];
    __syncthreads();
  }
  if (t == 0) stat[b] = M + logf(red[0]);
}

// ---------------- K5: out = logit - stat[b], float4 ----------------
__global__ __launch_bounds__(256) void k5_final(
    float* __restrict__ out, const float* __restrict__ stat) {
  const int total = BATCH * VOCAB;        // 6432896, divisible by 4
  int i4 = blockIdx.x * 256 + threadIdx.x;
  int base = i4 * 4;
  if (base >= total) return;
  float4 v = *(float4*)(out + base);
  int b0 = base / VOCAB, b3 = (base + 3) / VOCAB;
  if (b0 == b3) {
    float s = stat[b0];
    v.x -= s; v.y -= s; v.z -= s; v.w -= s;
  } else {
    v.x -= stat[base / VOCAB];
    v.y -= stat[(base + 1) / VOCAB];
    v.z -= stat[(base + 2) / VOCAB];
    v.w -= stat[(base + 3) / VOCAB];
  }
  *(float4*)(out + base) = v;
}

extern "C" void kernel_launch(void* const* d_in, const int* in_sizes, int n_in,
                              void* d_out, int out_size, void* d_ws, size_t ws_size,
                              hipStream_t stream) {
  const int*   ids   = (const int*)  d_in[0];
  const float* hprev = (const float*)d_in[1];
  // d_in[2] = encoder_output, unused by the reference
  const float* emb   = (const float*)d_in[3];
  const float* wih   = (const float*)d_in[4];
  const float* whh   = (const float*)d_in[5];
  const float* bih   = (const float*)d_in[6];
  const float* bhh   = (const float*)d_in[7];
  const float* Wout  = (const float*)d_in[8];
  const float* bout  = (const float*)d_in[9];
  float* out = (float*)d_out;
  char* ws = (char*)d_ws;

  // ws layout (bytes); max offset used = 12009472 (same as R3-R9).
  // hnbf2 aliases dead wihbf region; part/stat alias dead whhbf region.
  ushort_t* xbf   = (ushort_t*)(ws + 0);         // 128x320 bf16
  ushort_t* hbf   = (ushort_t*)(ws + 81920);     // 128x1024 bf16
  ushort_t* wihbf = (ushort_t*)(ws + 344064);    // 3072x320 bf16 (dead after k1)
  ushort_t* whhbf = (ushort_t*)(ws + 2310144);   // 3072x1024 bf16 (dead after k1)
  float*    gi    = (float*)(ws + 8601600);      // 128x3072 f32
  float*    gh    = (float*)(ws + 10174464);     // 128x3072 f32
  ushort_t* hnbf2 = (ushort_t*)(ws + 344064);    // 128x1024 bf16 chunk-major (aliases wihbf)
  float2*   part  = (float2*)(ws + 2310144);     // 786x128 float2 (aliases whhbf)
  float*    stat  = (float*)(ws + 5529600);      // 128 f32

  float* hnew_out = out + (size_t)BATCH * VOCAB;

  hipLaunchKernelGGL(k0_prep, dim3(6048), dim3(256), 0, stream,
                     ids, emb, hprev, wih, whh, xbf, hbf, wihbf, whhbf);
  hipLaunchKernelGGL(k1_gemm_gates, dim3(192, 2), dim3(64), 0, stream,
                     xbf, hbf, wihbf, whhbf, gi, gh);
  hipLaunchKernelGGL(k2_gates, dim3(64), dim3(256), 0, stream,
                     gi, gh, bih, bhh, hprev, hnew_out, hnbf2);
  hipLaunchKernelGGL(k3_logits, dim3(NBK3), dim3(64), 0, stream,
                     hnbf2, Wout, bout, out, part);
  hipLaunchKernelGGL(k4_combine, dim3(128), dim3(256), 0, stream, part, stat);
  hipLaunchKernelGGL(k5_final, dim3((BATCH * VOCAB / 4 + 255) / 256), dim3(256), 0, stream,
                     out, stat);
}